// Round 7
// baseline (12347.804 us; speedup 1.0000x reference)
//
#include <hip/hip_runtime.h>
#include <math.h>

#define B 16
#define S 32
#define T 64
#define H2 512
#define Hf 256
#define F 128
#define A 128
#define V 32000
#define SW 1024
#define NSTEP 63
#define VP1 32001
#define NBLK 256
#define LEADER 0

__device__ __forceinline__ float frcp(float x){ return __builtin_amdgcn_rcpf(x); }
__device__ __forceinline__ float fsigm(float x){ return frcp(1.f + __expf(-x)); }
__device__ __forceinline__ float ftanh_(float x){
    float e = __expf(-2.f*fabsf(x));
    float t = (1.f - e)*frcp(1.f + e);
    return x >= 0.f ? t : -t;
}
__device__ __forceinline__ float ald(const float* p){
    return __hip_atomic_load(p, __ATOMIC_RELAXED, __HIP_MEMORY_SCOPE_AGENT);
}
__device__ __forceinline__ void ast(float* p, float v){
    __hip_atomic_store(p, v, __ATOMIC_RELAXED, __HIP_MEMORY_SCOPE_AGENT);
}
__device__ __forceinline__ float2 ald2(const float* p){
    unsigned long long u = __hip_atomic_load((const unsigned long long*)p,
                            __ATOMIC_RELAXED, __HIP_MEMORY_SCOPE_AGENT);
    float2 r;
    r.x = __uint_as_float((unsigned)(u & 0xffffffffull));
    r.y = __uint_as_float((unsigned)(u >> 32));
    return r;
}

// grid barrier: RMW-free (round-6 design, measured equivalent-or-better).
__device__ __forceinline__ void gbar(unsigned* arr, unsigned* rel, unsigned gen){
    asm volatile("s_waitcnt vmcnt(0) lgkmcnt(0)" ::: "memory");
    __syncthreads();
    if (blockIdx.x == LEADER){
        if (threadIdx.x > 0 && threadIdx.x < NBLK){
            while (__hip_atomic_load(&arr[threadIdx.x*32], __ATOMIC_RELAXED,
                                     __HIP_MEMORY_SCOPE_AGENT) < gen)
                __builtin_amdgcn_s_sleep(2);
        }
        __syncthreads();
        if (threadIdx.x == 0)
            __hip_atomic_store(rel, gen, __ATOMIC_RELAXED, __HIP_MEMORY_SCOPE_AGENT);
        __syncthreads();
    } else {
        if (threadIdx.x == 0){
            __hip_atomic_store(&arr[blockIdx.x*32], gen, __ATOMIC_RELAXED,
                               __HIP_MEMORY_SCOPE_AGENT);
            while (__hip_atomic_load(rel, __ATOMIC_RELAXED,
                                     __HIP_MEMORY_SCOPE_AGENT) < gen)
                __builtin_amdgcn_s_sleep(4);
        }
        __syncthreads();
    }
}

// ---------------- init ----------------
__global__ __launch_bounds__(256) void k_init0(
    const float* __restrict__ state, const float* __restrict__ emb,
    const float* __restrict__ W_cc, const float* __restrict__ b_cc,
    const int* __restrict__ summary,
    float* __restrict__ x_g, float* __restrict__ out_g,
    float* __restrict__ cov_g, unsigned* __restrict__ cnt)
{
    int blk = blockIdx.x, tid = threadIdx.x;
    if (blk < 16){
        int b = blk;
        for (int j = tid; j < H2; j += 256)
            out_g[B*H2 + b*H2 + j] = state[b*2*H2 + j];   // h into buffer 1
        int tok = summary[b*T + 0];
        if (tid < F){
            float a = 0.f;
            for (int k = 0; k < F; ++k) a += emb[(size_t)tok*F + k]*W_cc[(size_t)k*F + tid];
            x_g[b*F + tid] = a + b_cc[tid];
        }
    } else {
        int j = blk - 16;
        for (int i = tid; i < 1024; i += 256) cov_g[j*1024 + i] = 0.f;
        if (j == 0){
            for (int i = tid; i < 8256; i += 256) cnt[i] = 0u;  // arr[256*32] + rel
        }
    }
}

// ---------------- precompute ws_aT[b][a][n] ----------------
__global__ __launch_bounds__(256) void k_wsa(
    const float* __restrict__ ws, const float* __restrict__ W_a, const float* __restrict__ b_a,
    float* __restrict__ ws_aT)
{
    __shared__ float wss2[512][20];
    int b = blockIdx.x, nt = blockIdx.y, tid = threadIdx.x;
    int n0 = nt*16;
    const float* wsrc = ws + ((size_t)(b*SW + n0))*H2;
    for (int i = tid; i < 16*512; i += 256){
        int n_l = i >> 9, k = i & 511;
        wss2[k][n_l] = wsrc[i];
    }
    __syncthreads();
    int a = tid & 127, nh = tid >> 7;
    float acc[8];
    float ba = b_a[a];
    #pragma unroll
    for (int j = 0; j < 8; ++j) acc[j] = ba;
    for (int k = 0; k < H2; ++k){
        float wa = W_a[k*A + a];
        const float4 u0 = *(const float4*)&wss2[k][nh*8];
        const float4 u1 = *(const float4*)&wss2[k][nh*8 + 4];
        acc[0] += u0.x*wa; acc[1] += u0.y*wa; acc[2] += u0.z*wa; acc[3] += u0.w*wa;
        acc[4] += u1.x*wa; acc[5] += u1.y*wa; acc[6] += u1.z*wa; acc[7] += u1.w*wa;
    }
    float* dst = ws_aT + ((size_t)(b*A + a))*SW + n0 + nh*8;
    #pragma unroll
    for (int j = 0; j < 8; ++j) dst[j] = acc[j];
}

// ---------------- Wf = W_rc @ W1_top ; bf = b_rc@W1_top + b1 ; bconst = b_rc@W_cc_bot ----
__global__ __launch_bounds__(256) void k_wf(
    const float* __restrict__ W_rc, const float* __restrict__ b_rc,
    const float* __restrict__ W1, const float* __restrict__ b1,
    const float* __restrict__ W_cc,
    float* __restrict__ Wf, float* __restrict__ bf, float* __restrict__ bconst)
{
    __shared__ float wrc[4][512];
    int j = blockIdx.x, tid = threadIdx.x;
    if (j < 256){
        for (int i = tid; i < 2048; i += 256){
            int kk = i >> 9, r = i & 511;
            wrc[kk][r] = W_rc[((size_t)(j*4 + kk))*H2 + r];
        }
        __syncthreads();
        float a0=0,a1=0,a2=0,a3=0;
        for (int r = 0; r < 512; ++r){
            float w1 = W1[(size_t)r*Hf + tid];
            a0 += wrc[0][r]*w1; a1 += wrc[1][r]*w1; a2 += wrc[2][r]*w1; a3 += wrc[3][r]*w1;
        }
        Wf[((size_t)(j*4+0))*Hf + tid] = a0;
        Wf[((size_t)(j*4+1))*Hf + tid] = a1;
        Wf[((size_t)(j*4+2))*Hf + tid] = a2;
        Wf[((size_t)(j*4+3))*Hf + tid] = a3;
    } else {
        float acc = b1[tid];
        for (int r = 0; r < 512; ++r) acc += b_rc[r]*W1[(size_t)r*Hf + tid];
        bf[tid] = acc;
        if (tid < 128){
            float a = 0.f;
            for (int c = 0; c < H2; ++c) a += b_rc[c]*W_cc[(size_t)(F+c)*F + tid];
            bconst[tid] = a;
        }
    }
}

// ---------------- WRCC = W_rc @ W_cc_bot ----------------
__global__ __launch_bounds__(128) void k_wrcc(
    const float* __restrict__ W_rc, const float* __restrict__ W_cc, float* __restrict__ WRCC)
{
    __shared__ float wr[512];
    int d = blockIdx.x, f = threadIdx.x;
    for (int i = f; i < 512; i += 128) wr[i] = W_rc[(size_t)d*H2 + i];
    __syncthreads();
    float a = 0.f;
    for (int c = 0; c < H2; ++c) a += wr[c]*W_cc[(size_t)(F+c)*F + f];
    WRCC[(size_t)d*F + f] = a;
}

// ---------------- embx[t][b] = emb[tok_t]@W_cc_top + b_cc ----------------
__global__ __launch_bounds__(128) void k_embx(
    const int* __restrict__ summary, const float* __restrict__ emb,
    const float* __restrict__ W_cc, const float* __restrict__ b_cc,
    float* __restrict__ embx)
{
    __shared__ float er[128];
    int t = blockIdx.x, b = blockIdx.y, f = threadIdx.x;
    int tok = summary[b*T + t];
    er[f] = emb[(size_t)tok*F + f];
    __syncthreads();
    float a = b_cc[f];
    for (int k = 0; k < F; ++k) a += er[k]*W_cc[(size_t)k*F + f];
    embx[((size_t)t*B + b)*F + f] = a;
}

// ---------------- persistent time-loop kernel ----------------
__global__ __launch_bounds__(256, 1) void k_persist(
    const float* __restrict__ ws, const float* __restrict__ ss,
    const int* __restrict__ text_length, const int* __restrict__ summary,
    const int* __restrict__ sumlen, const float* __restrict__ state,
    const float* __restrict__ Wx, const float* __restrict__ Wh,
    const float* __restrict__ b_lstm, const float* __restrict__ W_a,
    const float* __restrict__ v_a, const float* __restrict__ W1,
    const float* __restrict__ W2, const float* __restrict__ b2,
    const float* __restrict__ ws_aT, const float* __restrict__ Wf,
    const float* __restrict__ bf, const float* __restrict__ WRCC,
    const float* __restrict__ bconst, const float* __restrict__ embx,
    float* out_g, float* x_g, float* hid_g, float* wo_g, float* w1bz,
    float* scores_g, float* mpart, float* spart, float* c4_g,
    float* m2part, float* s2part, float* tgtlogit, float* covlp,
    float* cov_g, float* d_out, unsigned* cnt)
{
    __shared__ float BIG[10240];   // I: xh[16][640] (blk<64) | II: outs[16][514] (64..95) | IV: sc/attn/asum | V: c4
    __shared__ float WOLE[6168];   // persistent phase-II weights [12][514] (blocks 64..95)
    __shared__ float HIDL[4096];
    __shared__ float REDB[4096];   // gates red / logit_l[128][16] / IV,V partial red
    __shared__ float red3[512];
    __shared__ float red_l[256];
    __shared__ float red2_l[256];
    __shared__ float wo_l[128];
    __shared__ float wac_l[128];
    __shared__ float vas_l[128];
    __shared__ float score_l[64];
    __shared__ float cov_l[64];
    __shared__ float c_l[128];
    __shared__ float loss_l[16];
    __shared__ float misc[8];
    __shared__ int   tl_l[32];
    __shared__ int   sumlen_l[16];
    __shared__ int   tgt_l[16];

    const int blk = blockIdx.x, tid = threadIdx.x;
    unsigned* arr = cnt;
    unsigned* rel = cnt + 8192;

    // ---- resident weights ----
    float w2r[128]; float b2v;
    { int v = blk*128 + (tid>>1); int r0 = (tid&1)*128; bool ok = v < VP1;
      b2v = ok ? b2[v] : 0.f;
      #pragma unroll
      for (int i = 0; i < 128; ++i) w2r[i] = ok ? W2[(size_t)(r0+i)*VP1 + v] : 0.f; }
    float wsar[32];
    { int b3 = blk>>4; int n = (blk&15)*64 + (tid>>2); int a0 = (tid&3)*32;
      #pragma unroll
      for (int k = 0; k < 32; ++k) wsar[k] = ws_aT[((size_t)(b3*A + a0 + k))*SW + n]; }
    // gates weights (meaningful for blk<64): thread (cg=tid&31, kr=tid>>5)
    // covers (col = (blk&63)*8 + cg>>2, gate = cg&3, k in [kr*80, kr*80+80))
    const int cg = tid & 31, kr = tid >> 5;
    const int gcol = (blk & 63)*8 + (cg >> 2), ggate = cg & 3;
    float wgr[80];
    #pragma unroll
    for (int i = 0; i < 80; ++i){ int k = kr*80 + i;
        wgr[i] = (k < F) ? Wx[(size_t)k*2048 + ggate*512 + gcol]
                         : Wh[(size_t)(k-F)*2048 + ggate*512 + gcol]; }
    // Phase-II weights into LDS (blocks 64..95)
    if (blk >= 64 && blk < 96){
        int jj = blk - 64;
        for (int i = tid; i < 12*512; i += 256){
            int c = i >> 9, k = i & 511; int C = jj*12 + c;
            WOLE[c*514 + k] = (C < 128) ? W_a[(size_t)(H2 + k)*A + C]
                                        : W1[(size_t)(H2 + k)*Hf + (C - 128)];
        }
    }
    if (tid < 128){ wac_l[tid] = W_a[(size_t)(2*H2)*A + tid]; vas_l[tid] = v_a[tid]; }
    if (tid < 32) tl_l[tid] = text_length[(blk>>4)*S + tid];
    if (tid < 16){ sumlen_l[tid] = sumlen[tid]; loss_l[tid] = 0.f; }
    if (tid < 128){ int b = tid&15, cL = tid>>4;
        c_l[tid] = state[(size_t)b*2*H2 + H2 + (blk&63)*8 + cL]; }
    __syncthreads();

    unsigned gen = 0;
    for (int t = 0; t <= NSTEP; ++t){
        // ======== Phase I: gates(t) on blocks 0..63 | logits(t-1) on all ========
        if (t < NSTEP && blk < 64){
            const float* hsrc = out_g + ((t&1)^1)*(B*H2);
            #pragma unroll
            for (int k2 = 0; k2 < 20; ++k2){
                int p = k2*256 + tid;          // pair index < 5120
                int w = p*2;
                int b = w/640, off = w - b*640;
                float2 v;
                if (off < F) v = ald2(&x_g[b*F + off]);
                else {
                    v = ald2(&hsrc[b*H2 + off - F]);
                    float vp = (t==0) ? 1.f : ((sumlen_l[b] - t > 0) ? 1.f : 0.f);
                    v.x *= vp; v.y *= vp;
                }
                BIG[b*640 + off] = v.x; BIG[b*640 + off + 1] = v.y;
            }
        }
        if (t > 0){
            #pragma unroll
            for (int k2 = 0; k2 < 8; ++k2){
                int p = k2*256 + tid;          // 2048 pairs
                float2 v = ald2(&hid_g[p*2]);
                HIDL[p*2] = v.x; HIDL[p*2 + 1] = v.y;
            }
            if (tid < 16){ int tok = summary[tid*T + t]; tgt_l[tid] = (tok==-1)?V:tok; }
        }
        __syncthreads();
        if (t < NSTEP && blk < 64){
            for (int b = 0; b < 16; ++b){
                float a = 0.f;
                const float* xb = &BIG[b*640 + kr*80];
                #pragma unroll
                for (int i = 0; i < 80; ++i) a = fmaf(xb[i], wgr[i], a);
                REDB[(b*8 + kr)*32 + cg] = a;
            }
            __syncthreads();
            #pragma unroll
            for (int oo = 0; oo < 2; ++oo){
                int o = oo*256 + tid;          // < 512
                int b = o>>5, cgp = o&31;
                float s = 0.f;
                #pragma unroll
                for (int k8 = 0; k8 < 8; ++k8) s += REDB[(b*8 + k8)*32 + cgp];
                red3[o] = s;
            }
            __syncthreads();
            if (tid < 128){
                int b = tid&15, cL = tid>>4, col = blk*8 + cL;
                float gi = red3[b*32 + cL*4 + 0] + b_lstm[col];
                float gf = red3[b*32 + cL*4 + 1] + b_lstm[H2 + col];
                float gg = red3[b*32 + cL*4 + 2] + b_lstm[2*H2 + col];
                float go = red3[b*32 + cL*4 + 3] + b_lstm[3*H2 + col];
                float cold = c_l[tid];
                float cn = fsigm(gf)*cold + fsigm(gi)*ftanh_(gg);
                float o2 = fsigm(go)*ftanh_(cn);
                float valid = (sumlen_l[b] - t - 1 > 0) ? 1.f : 0.f;
                c_l[tid] = cn*valid;
                ast(&out_g[(t&1)*(B*H2) + b*H2 + col], o2);
            }
        }
        if (t > 0){
            __syncthreads();                   // REDB now reused as logit_l[128][16]
            float* logit_l = REDB;
            int v = blk*128 + (tid>>1), r0 = (tid&1)*128;
            bool ok = v < VP1;
            for (int b = 0; b < 16; ++b){
                const float4* h4 = (const float4*)&HIDL[b*256 + r0];
                float a = 0.f;
                #pragma unroll
                for (int i = 0; i < 32; ++i){ float4 h = h4[i];
                    a = fmaf(h.x, w2r[4*i],   a); a = fmaf(h.y, w2r[4*i+1], a);
                    a = fmaf(h.z, w2r[4*i+2], a); a = fmaf(h.w, w2r[4*i+3], a); }
                a += __shfl_xor(a, 1);
                if ((tid&1) == 0){
                    float lg = ok ? (a + b2v) : -1e30f;
                    logit_l[(tid>>1)*16 + b] = lg;
                    if (ok && v == tgt_l[b]) ast(&tgtlogit[b], lg);
                }
            }
            __syncthreads();
            int b = tid&15, cgr = tid>>4;
            float m8 = -1e30f;
            #pragma unroll
            for (int i = 0; i < 8; ++i) m8 = fmaxf(m8, logit_l[(cgr*8+i)*16 + b]);
            red2_l[b*16 + cgr] = m8;
            __syncthreads();
            if (tid < 16){ float m = -1e30f;
                for (int i = 0; i < 16; ++i) m = fmaxf(m, red2_l[tid*16+i]);
                red_l[tid] = m; }
            __syncthreads();
            float Mb = red_l[b];
            float s8 = 0.f;
            #pragma unroll
            for (int i = 0; i < 8; ++i) s8 += __expf(logit_l[(cgr*8+i)*16 + b] - Mb);
            red2_l[b*16 + cgr] = s8;
            __syncthreads();
            if (tid < 16){ float s = 0.f;
                for (int i = 0; i < 16; ++i) s += red2_l[tid*16+i];
                ast(&m2part[tid*256 + blk], red_l[tid]);
                ast(&s2part[tid*256 + blk], s); }
        }
        gen++; gbar(arr, rel, gen);

        // ======== Phase II: wo + w1b (blocks 64..95) | loss-merge(t-1) (blk 255) ========
        if (t < NSTEP && blk >= 64 && blk < 96){
            const float* outc = out_g + (t&1)*(B*H2);
            #pragma unroll
            for (int k2 = 0; k2 < 16; ++k2){
                int p = k2*256 + tid;          // 4096 pairs
                int b = p >> 8, j2 = p & 255;
                float2 vv = ald2(&outc[b*H2 + j2*2]);
                BIG[b*514 + j2*2] = vv.x; BIG[b*514 + j2*2 + 1] = vv.y;
            }
            __syncthreads();
            if (tid < 192){
                int b = tid & 15, c = tid >> 4;
                int C = (blk - 64)*12 + c;
                const float* ob = &BIG[b*514];
                const float* wl = &WOLE[c*514];
                float a = 0.f;
                #pragma unroll 4
                for (int k = 0; k < 512; k += 2){
                    a = fmaf(ob[k], wl[k], a);
                    a = fmaf(ob[k+1], wl[k+1], a);
                }
                if (C < 128) ast(&wo_g[b*128 + C], a);
                else         ast(&w1bz[b*256 + (C - 128)], a);
            }
        }
        if (t > 0 && blk == 255){
            int tf = t - 1, b = tid>>4, g = tid&15;
            float mv[16];
            #pragma unroll
            for (int i = 0; i < 16; ++i) mv[i] = ald(&m2part[b*256 + g*16 + i]);
            float M = -1e30f;
            #pragma unroll
            for (int i = 0; i < 16; ++i) M = fmaxf(M, mv[i]);
            #pragma unroll
            for (int off = 1; off < 16; off <<= 1) M = fmaxf(M, __shfl_xor(M, off, 16));
            float sden = 0.f;
            #pragma unroll
            for (int i = 0; i < 16; ++i)
                sden += ald(&s2part[b*256 + g*16 + i]) * __expf(mv[i] - M);
            #pragma unroll
            for (int off = 1; off < 16; off <<= 1) sden += __shfl_xor(sden, off, 16);
            if (g == 0){
                float tlg = ald(&tgtlogit[b]);
                float cl4 = ald(&covlp[b*4+0]) + ald(&covlp[b*4+1])
                          + ald(&covlp[b*4+2]) + ald(&covlp[b*4+3]);
                float logp = tlg - M - __logf(sden);
                float valid = (sumlen_l[b] - tf - 1 > 0) ? 1.f : 0.f;
                loss_l[b] += valid*(-logp + cl4);
                if (t == NSTEP) d_out[b] = loss_l[b] / ((float)sumlen_l[b] - 1.f);
            }
        }
        if (t == NSTEP) break;
        gen++; gbar(arr, rel, gen);

        // ======== Phase III: attention scores (b = blk>>4, 64 n per block) ========
        {
            int b = blk>>4, sl = blk&15;
            if (tid < 64){ float2 vv = ald2(&wo_g[b*128 + tid*2]);
                wo_l[tid*2] = vv.x; wo_l[tid*2+1] = vv.y; }
            else if (tid < 96){ int q = tid - 64;
                float2 cvv = ald2(&cov_g[b*SW + sl*64 + q*2]);
                cov_l[q*2] = cvv.x; cov_l[q*2+1] = cvv.y; }
            __syncthreads();
            int nl = tid>>2, ai = tid&3, a0 = ai*32;
            float cv = cov_l[nl];
            float acc = 0.f;
            #pragma unroll
            for (int k = 0; k < 32; ++k){
                float arg = wsar[k] + wo_l[a0+k] + cv*wac_l[a0+k];
                acc = fmaf(ftanh_(arg), vas_l[a0+k], acc);
            }
            acc += __shfl_xor(acc, 1);
            acc += __shfl_xor(acc, 2);
            if (ai == 0){
                int n = sl*64 + nl;
                float sc = ((n&31) < tl_l[n>>5]) ? acc : -1e9f;
                score_l[nl] = sc;
                ast(&scores_g[b*SW + n], sc);
            }
            __syncthreads();
            if (tid == 0){
                float m = score_l[0];
                for (int i = 1; i < 64; ++i) m = fmaxf(m, score_l[i]);
                float s = 0.f;
                for (int i = 0; i < 64; ++i) s += __expf(score_l[i] - m);
                ast(&mpart[b*16 + sl], m);
                ast(&spart[b*16 + sl], s);
            }
        }
        gen++; gbar(arr, rel, gen);

        // ======== Phase IV: c4 direct (r<8) | coverage+covloss (r 8..11) ========
        {
            int b = blk>>4, r = blk&15;
            if (r < 8){
                float* sc4   = BIG;            // 1024
                float* attn4 = BIG + 1024;     // 1024
                float* asum4 = BIG + 2048;     // 32
                if (tid < 16) red_l[tid] = ald(&mpart[b*16 + tid]);
                else if (tid < 32) red_l[tid] = ald(&spart[b*16 + tid - 16]);
                { float2 v0 = ald2(&scores_g[b*SW + tid*2]);
                  sc4[tid*2] = v0.x; sc4[tid*2+1] = v0.y;
                  float2 v1 = ald2(&scores_g[b*SW + 512 + tid*2]);
                  sc4[512 + tid*2] = v1.x; sc4[512 + tid*2 + 1] = v1.y; }
                __syncthreads();
                if (tid == 0){
                    float M = -1e30f;
                    for (int i = 0; i < 16; ++i) M = fmaxf(M, red_l[i]);
                    float Sv = 0.f;
                    for (int i = 0; i < 16; ++i) Sv += red_l[16+i]*__expf(red_l[i] - M);
                    misc[0] = M; misc[1] = frcp(Sv);
                }
                __syncthreads();
                #pragma unroll
                for (int q = 0; q < 4; ++q){ int n = q*256 + tid;
                    attn4[n] = __expf(sc4[n] - misc[0])*misc[1]; }
                __syncthreads();
                if (tid < 32){
                    float s = 0.f;
                    #pragma unroll
                    for (int w = 0; w < 32; ++w) s += attn4[tid*32 + ((w + tid)&31)];
                    asum4[tid] = s;
                }
                int d = r*64 + (tid&63), nq = tid>>6;
                float acc = 0.f;
                const float* wsb = ws + ((size_t)(b*SW) + nq*256)*H2 + d;
                #pragma unroll 4
                for (int j = 0; j < 256; ++j)
                    acc = fmaf(attn4[nq*256 + j], wsb[(size_t)j*H2], acc);
                REDB[nq*80 + (tid&63)] = acc;
                __syncthreads();
                if (tid < 64){
                    float c4v = REDB[tid] + REDB[80+tid] + REDB[160+tid] + REDB[240+tid];
                    ast(&c4_g[b*1024 + r*64 + tid], c4v);
                    float sa = 0.f;
                    const float* ssb = ss + ((size_t)(b*S))*H2 + r*64 + tid;
                    #pragma unroll
                    for (int s2 = 0; s2 < 32; ++s2) sa = fmaf(asum4[s2], ssb[(size_t)s2*H2], sa);
                    ast(&c4_g[b*1024 + 512 + r*64 + tid], sa);
                }
            } else if (r < 12){
                if (tid < 16) red_l[tid] = ald(&mpart[b*16 + tid]);
                else if (tid < 32) red_l[tid] = ald(&spart[b*16 + tid - 16]);
                __syncthreads();
                if (tid == 0){
                    float M = -1e30f;
                    for (int i = 0; i < 16; ++i) M = fmaxf(M, red_l[i]);
                    float Sv = 0.f;
                    for (int i = 0; i < 16; ++i) Sv += red_l[16+i]*__expf(red_l[i] - M);
                    misc[0] = M; misc[1] = frcp(Sv);
                }
                __syncthreads();
                int n = (r - 8)*256 + tid;
                float sc = ald(&scores_g[b*SW + n]);
                float at = __expf(sc - misc[0])*misc[1];
                float cv = ald(&cov_g[b*SW + n]);
                float valid = (sumlen_l[b] - t - 1 > 0) ? 1.f : 0.f;
                ast(&cov_g[b*SW + n], cv + at*valid);
                red2_l[tid] = fminf(cv, at);
                __syncthreads();
                for (int off = 128; off > 0; off >>= 1){
                    if (tid < off) red2_l[tid] += red2_l[tid + off];
                    __syncthreads();
                }
                if (tid == 0) ast(&covlp[b*4 + (r - 8)], red2_l[0]);
            }
        }
        gen++; gbar(arr, rel, gen);

        // ======== Phase V: hid (r<8) | x (r 8..11) ========
        {
            int b = blk>>4, r = blk&15;
            if (r < 12){
                float* c4l = BIG;
                { float2 v0 = ald2(&c4_g[b*1024 + tid*2]);
                  c4l[tid*2] = v0.x; c4l[tid*2+1] = v0.y;
                  float2 v1 = ald2(&c4_g[b*1024 + 512 + tid*2]);
                  c4l[512 + tid*2] = v1.x; c4l[512 + tid*2 + 1] = v1.y; }
                __syncthreads();
                int cl = tid&31, kq = tid>>5;
                if (r < 8){
                    int col = r*32 + cl;
                    float a = 0.f;
                    const float* wp = Wf + (size_t)(kq*128)*Hf + col;
                    #pragma unroll 4
                    for (int i = 0; i < 128; ++i) a = fmaf(c4l[kq*128 + i], wp[(size_t)i*Hf], a);
                    REDB[kq*40 + cl] = a;
                    __syncthreads();
                    if (tid < 32){
                        float z = 0.f;
                        #pragma unroll
                        for (int k8 = 0; k8 < 8; ++k8) z += REDB[k8*40 + tid];
                        z += ald(&w1bz[b*256 + r*32 + tid]) + bf[r*32 + tid];
                        ast(&hid_g[b*256 + r*32 + tid], fmaxf(z, 0.f));
                    }
                } else {
                    int f = (r - 8)*32 + cl;
                    float a = 0.f;
                    const float* wp = WRCC + (size_t)(kq*128)*F + f;
                    #pragma unroll 4
                    for (int i = 0; i < 128; ++i) a = fmaf(c4l[kq*128 + i], wp[(size_t)i*F], a);
                    REDB[kq*40 + cl] = a;
                    __syncthreads();
                    if (tid < 32){
                        int f2 = (r - 8)*32 + tid;
                        float z = 0.f;
                        #pragma unroll
                        for (int k8 = 0; k8 < 8; ++k8) z += REDB[k8*40 + tid];
                        float valid = (sumlen_l[b] - t - 1 > 0) ? 1.f : 0.f;
                        float xv = embx[((size_t)(t+1)*B + b)*F + f2] + valid*(z + bconst[f2]);
                        ast(&x_g[b*F + f2], xv);
                    }
                }
            }
        }
        gen++; gbar(arr, rel, gen);
    }
}

extern "C" void kernel_launch(void* const* d_in, const int* in_sizes, int n_in,
                              void* d_out, int out_size, void* d_ws, size_t ws_size,
                              hipStream_t stream) {
    const float* text_states = (const float*)d_in[0];
    const float* sent_states = (const float*)d_in[1];
    const int*   text_length = (const int*)d_in[2];
    const float* state       = (const float*)d_in[3];
    const int*   summary     = (const int*)d_in[4];
    const int*   sumlen      = (const int*)d_in[5];
    const float* emb    = (const float*)d_in[6];
    const float* W_cc   = (const float*)d_in[7];
    const float* b_cc   = (const float*)d_in[8];
    const float* Wx     = (const float*)d_in[9];
    const float* Wh     = (const float*)d_in[10];
    const float* b_lstm = (const float*)d_in[11];
    const float* W_a    = (const float*)d_in[12];
    const float* b_a    = (const float*)d_in[13];
    const float* v_a    = (const float*)d_in[14];
    const float* W_rc   = (const float*)d_in[15];
    const float* b_rc   = (const float*)d_in[16];
    const float* W1     = (const float*)d_in[17];
    const float* b1     = (const float*)d_in[18];
    const float* W2     = (const float*)d_in[19];
    const float* b2     = (const float*)d_in[20];
    float* out = (float*)d_out;

    float* p = (float*)d_ws;
    float* ws_aT    = p; p += (size_t)B*A*SW;      // 2,097,152
    float* Wf       = p; p += (size_t)1024*Hf;     // 262,144
    float* bfv      = p; p += Hf;                  // 256
    float* WRCC     = p; p += (size_t)1024*F;      // 131,072
    float* bconst   = p; p += F;                   // 128
    float* embx     = p; p += (size_t)T*B*F;       // 131,072
    float* out_g    = p; p += 2*B*H2;              // 16,384
    float* x_g      = p; p += B*F;                 // 2,048
    float* hid_g    = p; p += B*Hf;                // 4,096
    float* wo_g     = p; p += B*A;                 // 2,048
    float* w1bz     = p; p += B*Hf;                // 4,096
    float* scores_g = p; p += B*SW;                // 16,384
    float* mpart    = p; p += B*16;                // 256
    float* spart    = p; p += B*16;                // 256
    float* c4_g     = p; p += (size_t)B*1024;      // 16,384
    float* m2part   = p; p += B*256;               // 4,096
    float* s2part   = p; p += B*256;               // 4,096
    float* tgtlog   = p; p += B;                   // 16
    float* covlp    = p; p += B*4;                 // 64
    float* cov_g    = p; p += B*SW;                // 16,384
    unsigned* cnt   = (unsigned*)p;

    k_init0<<<32, 256, 0, stream>>>(state, emb, W_cc, b_cc, summary, x_g, out_g, cov_g, cnt);
    k_wsa<<<dim3(B, 64), 256, 0, stream>>>(text_states, W_a, b_a, ws_aT);
    k_wf<<<257, 256, 0, stream>>>(W_rc, b_rc, W1, b1, W_cc, Wf, bfv, bconst);
    k_wrcc<<<1024, 128, 0, stream>>>(W_rc, W_cc, WRCC);
    k_embx<<<dim3(T, B), 128, 0, stream>>>(summary, emb, W_cc, b_cc, embx);
    k_persist<<<NBLK, 256, 0, stream>>>(
        text_states, sent_states, text_length, summary, sumlen, state,
        Wx, Wh, b_lstm, W_a, v_a, W1, W2, b2,
        ws_aT, Wf, bfv, WRCC, bconst, embx,
        out_g, x_g, hid_g, wo_g, w1bz, scores_g, mpart, spart, c4_g,
        m2part, s2part, tgtlog, covlp, cov_g, out, cnt);
}